// Round 4
// baseline (36269.226 us; speedup 1.0000x reference)
//
#include <hip/hip_runtime.h>
#include <cmath>

// ============================================================================
// Fused 2-layer GRU (B=128, T=512, d=512) + projection, fp32.
// ONE persistent cooperative kernel, 256 WGs x 256 thr (1 WG/CU).
// Pipeline skew: iter g computes L0 step g AND L1 step g-1.
//   - W_hh0, W_hh1 resident in LDS (swizzled); W_ih1 streamed from L2
//   - h0/h1 ping-pong in __device__ globals (no d_ws dependency at all);
//     initial-state reads replaced by g==0 / g<=1 guards (no zero-init needed)
//   - 16-way K-split (4 lane-groups x 4 waves), shfl + LDS reduce
//   - one 64-WG barrier per iter (4 independent batch groups), 513 iters;
//     counters zeroed by a stream-ordered micro-kernel each launch
// Desk-verified r3: gate algebra (r,z,n), sc0/sc1 ownership, ping-pong parity,
// release/acquire barrier protocol, LDS bank conflicts (<=2-way), budgets.
// ============================================================================

#define TSEQ   512
#define NB     128
#define DM     512
#define ENCF   21
#define PREDL  96
#define TSTART 416
#define NTHR   256
#define NBLK   256

// LDS layout (float indices)
#define L_WHH0 0                    // [24][512] swizzled
#define L_WHH1 (24*DM)              // [24][512] swizzled
#define L_HCH  (2*24*DM)            // [32][128] swizzled h chunk
#define L_SC0  (L_HCH + 32*128)     // [4][32][33] reduce scratch L0
#define L_SC1  (L_SC0 + 4*32*33)    // [4][32][33] reduce scratch L1
#define L_BIA0 (L_SC1 + 4*32*33)    // 48: [0..23]=bhh0 rows, [24..47]=bih0 rows
#define L_BIA1 (L_BIA0 + 48)        // 48
#define L_WIH0 (L_BIA1 + 48)        // [24][24] (K=21 padded)
#define L_XCH  (L_WIH0 + 24*24)     // [32][24] x slice
#define L_WP   (L_XCH + 32*24)      // [21][8] W_proj slice
#define L_HNT  (L_WP + 168)         // [32][8] h1 tile for projection
#define LDS_FLOATS (L_HNT + 256)    // 38,984 floats = 155,936 B  (<160 KiB)
#define LDS_BYTES  (LDS_FLOATS * 4)

__device__ float g_h0A[NB * DM];
__device__ float g_h0B[NB * DM];
__device__ float g_h1A[NB * DM];
__device__ float g_h1B[NB * DM];
__device__ unsigned g_bar[16];

extern "C" __global__ void zero_bar_kernel() {
  if (threadIdx.x < 16) g_bar[threadIdx.x] = 0u;
}

__device__ __forceinline__ float sigf(float x) { return 1.0f / (1.0f + expf(-x)); }

extern "C" __global__ __launch_bounds__(NTHR, 1)
void gru2_fused(const float* __restrict__ x_enc,
                const float* __restrict__ Wih0, const float* __restrict__ Whh0,
                const float* __restrict__ bih0, const float* __restrict__ bhh0,
                const float* __restrict__ Wih1, const float* __restrict__ Whh1,
                const float* __restrict__ bih1, const float* __restrict__ bhh1,
                const float* __restrict__ Wproj, const float* __restrict__ bproj,
                float* __restrict__ outp)
{
  extern __shared__ float lds[];

  const int tid = threadIdx.x;
  const int bid = blockIdx.x;
  const int bt  = bid & 3;         // batch group (32 rows), barrier group
  const int jt  = bid >> 2;        // j tile 0..63 (8 hidden units)
  const int b0  = bt << 5;
  const int j0  = jt << 3;
  const int l   = tid & 63;
  const int wv  = tid >> 6;        // wave 0..3
  const int pr  = l & 3;           // row position (bits 0-1)
  const int pb4 = (l >> 2) & 3;    // batch position mod 4 (bits 2-3)
  const int kg  = l >> 4;          // k-group within wave (bits 4-5)

  const float4 z4 = make_float4(0.f, 0.f, 0.f, 0.f);

  // ---- one-time staging: W_hh0/W_hh1 (swizzled), W_ih0, biases, W_proj ----
  // tile row r in 0..23 -> global row R = (r>>3)*512 + j0 + (r&7); gates r,z,n
  for (int f = tid; f < 24 * 128; f += NTHR) {
    int r = f >> 7, w4 = f & 127;
    int R = ((r >> 3) << 9) + j0 + (r & 7);
    int dst = r * DM + ((w4 << 2) ^ ((r & 3) << 2));   // bank swizzle by row
    *(float4*)(lds + L_WHH0 + dst) = *(const float4*)(Whh0 + (size_t)R * DM + (w4 << 2));
    *(float4*)(lds + L_WHH1 + dst) = *(const float4*)(Whh1 + (size_t)R * DM + (w4 << 2));
  }
  for (int idx = tid; idx < 24 * ENCF; idx += NTHR) {
    int r = idx / ENCF, kx = idx - r * ENCF;
    int R = ((r >> 3) << 9) + j0 + (r & 7);
    lds[L_WIH0 + r * 24 + kx] = Wih0[R * ENCF + kx];
  }
  if (tid < 24) {
    int R = ((tid >> 3) << 9) + j0 + (tid & 7);
    lds[L_BIA0 + tid]      = bhh0[R];
    lds[L_BIA0 + 24 + tid] = bih0[R];
    lds[L_BIA1 + tid]      = bhh1[R];
    lds[L_BIA1 + 24 + tid] = bih1[R];
  }
  for (int idx = tid; idx < 21 * 8; idx += NTHR) {
    int o = idx >> 3, j = idx & 7;
    lds[L_WP + idx] = Wproj[o * DM + j0 + j];
  }
  // visibility covered by first __syncthreads in the chunk loop

#pragma unroll 1
  for (int g = 0; g <= TSEQ; ++g) {
    // ping-pong: h0_g -> buf0[g&1]; h1_{g-1} -> buf1[(g-1)&1]
    const float* h0r = (g & 1) ? g_h0A : g_h0B;   // h0_{g-1}
    float*       h0w = (g & 1) ? g_h0B : g_h0A;   // h0_g
    const float* h1r = (g & 1) ? g_h1B : g_h1A;   // h1_{g-2}
    float*       h1w = (g & 1) ? g_h1A : g_h1B;   // h1_{g-1}

    // x slice prefetch (regs); clamp at g==TSEQ (L0 result unused there)
    const int gx = (g < TSEQ) ? g : (TSEQ - 1);
    float rx[3];
#pragma unroll
    for (int q = 0; q < 3; ++q) {
      int idx = tid + (q << 8);
      float v = 0.0f;
      if (idx < 32 * ENCF) {
        int row = idx / ENCF, kx = idx - row * ENCF;
        v = x_enc[((size_t)(b0 + row) * TSEQ + gx) * ENCF + kx];
      }
      rx[q] = v;
    }

    float accA[8][6], accX[8][6];
#pragma unroll
    for (int i = 0; i < 8; ++i)
#pragma unroll
      for (int m = 0; m < 6; ++m) { accA[i][m] = 0.0f; accX[i][m] = 0.0f; }

    // h0 chunk-0 prefetch (g==0: initial state is zero, skip the load)
    float4 ph[4];
#pragma unroll
    for (int q = 0; q < 4; ++q) {
      int f = tid + (q << 8);
      int row = f >> 5, w4 = f & 31;
      ph[q] = (g == 0) ? z4
            : *(const float4*)(h0r + (size_t)(b0 + row) * DM + (w4 << 2));
    }

    // ---- pass A+B: h0_{g-1} x (W_hh0 from LDS, W_ih1 from global) ----
#pragma unroll 1
    for (int c = 0; c < 4; ++c) {
      __syncthreads();                             // prev chunk compute done
#pragma unroll
      for (int q = 0; q < 4; ++q) {
        int f = tid + (q << 8);
        int row = f >> 5, w4 = f & 31;
        *(float4*)(lds + L_HCH + row * 128 + ((w4 << 2) ^ ((row & 3) << 2))) = ph[q];
      }
      __syncthreads();
      if (c < 3) {
#pragma unroll
        for (int q = 0; q < 4; ++q) {
          int f = tid + (q << 8);
          int row = f >> 5, w4 = f & 31;
          ph[q] = (g == 0) ? z4
                : *(const float4*)(h0r + (size_t)(b0 + row) * DM + ((c + 1) << 7) + (w4 << 2));
        }
      }
      // issue global W_ih1 loads (L2-resident, disjoint rows per jt)
      float4 wx[6][2];
#pragma unroll
      for (int m = 0; m < 6; ++m) {
        int r = pr + (m << 2);
        int R = ((r >> 3) << 9) + j0 + (r & 7);
#pragma unroll
        for (int q = 0; q < 2; ++q) {
          int ww = (wv << 3) + (kg << 1) + q;
          wx[m][q] = *(const float4*)(Wih1 + (size_t)R * DM + (((c << 5) + ww) << 2));
        }
      }
#pragma unroll
      for (int q = 0; q < 2; ++q) {
        int ww = (wv << 3) + (kg << 1) + q;
        int colf = ((c << 5) + ww) << 2;
        float4 wh[6];
#pragma unroll
        for (int m = 0; m < 6; ++m) {
          int r = pr + (m << 2);
          wh[m] = *(const float4*)(lds + L_WHH0 + r * DM + (colf ^ ((r & 3) << 2)));
        }
#pragma unroll
        for (int i = 0; i < 8; ++i) {
          int b = pb4 + (i << 2);
          float4 hv = *(const float4*)(lds + L_HCH + b * 128 + ((ww << 2) ^ ((b & 3) << 2)));
#pragma unroll
          for (int m = 0; m < 6; ++m) {
            accA[i][m] += hv.x * wh[m].x + hv.y * wh[m].y + hv.z * wh[m].z + hv.w * wh[m].w;
            accX[i][m] += hv.x * wx[m][q].x + hv.y * wx[m][q].y + hv.z * wx[m][q].z + hv.w * wx[m][q].w;
          }
        }
      }
    }

    // reduce A -> sc0 (=), X -> sc1 (=)
#pragma unroll
    for (int i = 0; i < 8; ++i)
#pragma unroll
      for (int m = 0; m < 6; ++m) {
        float a = accA[i][m]; a += __shfl_xor(a, 16); a += __shfl_xor(a, 32); accA[i][m] = a;
        float x = accX[i][m]; x += __shfl_xor(x, 16); x += __shfl_xor(x, 32); accX[i][m] = x;
      }
    if (kg == 0) {
#pragma unroll
      for (int i = 0; i < 8; ++i) {
        int b = pb4 + (i << 2);
        float* s0 = lds + L_SC0 + (wv * 32 + b) * 33;
        float* s1 = lds + L_SC1 + (wv * 32 + b) * 33;
#pragma unroll
        for (int m = 0; m < 6; ++m) {
          int r = pr + (m << 2);
          s0[r] = accA[i][m];
          s1[(m < 4) ? r : (r + 8)] = accX[i][m];   // n-gate x-part at 24..31
        }
      }
    }

    // ---- pass C: h1_{g-2} x W_hh1 (LDS) ----
#pragma unroll
    for (int q = 0; q < 4; ++q) {
      int f = tid + (q << 8);
      int row = f >> 5, w4 = f & 31;
      ph[q] = (g <= 1) ? z4
            : *(const float4*)(h1r + (size_t)(b0 + row) * DM + (w4 << 2));
    }
#pragma unroll
    for (int i = 0; i < 8; ++i)
#pragma unroll
      for (int m = 0; m < 6; ++m) accA[i][m] = 0.0f;

#pragma unroll 1
    for (int c = 0; c < 4; ++c) {
      __syncthreads();
#pragma unroll
      for (int q = 0; q < 4; ++q) {
        int f = tid + (q << 8);
        int row = f >> 5, w4 = f & 31;
        *(float4*)(lds + L_HCH + row * 128 + ((w4 << 2) ^ ((row & 3) << 2))) = ph[q];
      }
      __syncthreads();
      if (c < 3) {
#pragma unroll
        for (int q = 0; q < 4; ++q) {
          int f = tid + (q << 8);
          int row = f >> 5, w4 = f & 31;
          ph[q] = (g <= 1) ? z4
                : *(const float4*)(h1r + (size_t)(b0 + row) * DM + ((c + 1) << 7) + (w4 << 2));
        }
      }
#pragma unroll
      for (int q = 0; q < 2; ++q) {
        int ww = (wv << 3) + (kg << 1) + q;
        int colf = ((c << 5) + ww) << 2;
        float4 wh[6];
#pragma unroll
        for (int m = 0; m < 6; ++m) {
          int r = pr + (m << 2);
          wh[m] = *(const float4*)(lds + L_WHH1 + r * DM + (colf ^ ((r & 3) << 2)));
        }
#pragma unroll
        for (int i = 0; i < 8; ++i) {
          int b = pb4 + (i << 2);
          float4 hv = *(const float4*)(lds + L_HCH + b * 128 + ((ww << 2) ^ ((b & 3) << 2)));
#pragma unroll
          for (int m = 0; m < 6; ++m)
            accA[i][m] += hv.x * wh[m].x + hv.y * wh[m].y + hv.z * wh[m].z + hv.w * wh[m].w;
        }
      }
    }

    // reduce C -> sc1: rows 0..15 (+=, join x-part), rows 16..23 (=, h-part)
#pragma unroll
    for (int i = 0; i < 8; ++i)
#pragma unroll
      for (int m = 0; m < 6; ++m) {
        float a = accA[i][m]; a += __shfl_xor(a, 16); a += __shfl_xor(a, 32); accA[i][m] = a;
      }
    if (kg == 0) {
#pragma unroll
      for (int i = 0; i < 8; ++i) {
        int b = pb4 + (i << 2);
        float* s1 = lds + L_SC1 + (wv * 32 + b) * 33;
#pragma unroll
        for (int m = 0; m < 6; ++m) {
          int r = pr + (m << 2);
          if (m < 4) s1[r] += accA[i][m];          // same thread wrote '=' above
          else       s1[r]  = accA[i][m];
        }
      }
    }

    // stage x slice for L0 gate threads
#pragma unroll
    for (int q = 0; q < 3; ++q) {
      int idx = tid + (q << 8);
      if (idx < 32 * ENCF) {
        int row = idx / ENCF, kx = idx - row * ENCF;
        lds[L_XCH + row * 24 + kx] = rx[q];
      }
    }
    __syncthreads();

    // ---- gates: thread -> (b = tid>>3, j = tid&7) ----
    {
      int b = tid >> 3, j = tid & 7;
      float sR0 = 0.f, sZ0 = 0.f, sN0 = 0.f;
      float sR1 = 0.f, sZ1 = 0.f, sN1h = 0.f, sN1x = 0.f;
#pragma unroll
      for (int w = 0; w < 4; ++w) {
        const float* s0 = lds + L_SC0 + (w * 32 + b) * 33;
        const float* s1 = lds + L_SC1 + (w * 32 + b) * 33;
        sR0 += s0[j]; sZ0 += s0[8 + j]; sN0 += s0[16 + j];
        sR1 += s1[j]; sZ1 += s1[8 + j]; sN1h += s1[16 + j]; sN1x += s1[24 + j];
      }
      size_t hix = (size_t)(b0 + b) * DM + j0 + j;
      if (g < TSEQ) {
        float xr = 0.f, xz = 0.f, xn = 0.f;
        const float* xrow = lds + L_XCH + b * 24;
#pragma unroll
        for (int k = 0; k < ENCF; ++k) {
          float xv = xrow[k];
          xr += xv * lds[L_WIH0 + j * 24 + k];
          xz += xv * lds[L_WIH0 + (8 + j) * 24 + k];
          xn += xv * lds[L_WIH0 + (16 + j) * 24 + k];
        }
        float h0prev = (g == 0) ? 0.f : h0r[hix];
        float r0 = sigf(xr + lds[L_BIA0 + 24 + j] + sR0 + lds[L_BIA0 + j]);
        float z0 = sigf(xz + lds[L_BIA0 + 32 + j] + sZ0 + lds[L_BIA0 + 8 + j]);
        float n0 = tanhf(xn + lds[L_BIA0 + 40 + j] + r0 * (sN0 + lds[L_BIA0 + 16 + j]));
        h0w[hix] = (1.0f - z0) * n0 + z0 * h0prev;
      }
      if (g >= 1) {
        float h1prev = (g == 1) ? 0.f : h1r[hix];
        float r1 = sigf(sR1 + lds[L_BIA1 + 24 + j] + lds[L_BIA1 + j]);
        float z1 = sigf(sZ1 + lds[L_BIA1 + 32 + j] + lds[L_BIA1 + 8 + j]);
        float n1 = tanhf(sN1x + lds[L_BIA1 + 40 + j] + r1 * (sN1h + lds[L_BIA1 + 16 + j]));
        float h1n = (1.0f - z1) * n1 + z1 * h1prev;
        h1w[hix] = h1n;
        lds[L_HNT + (b << 3) + j] = h1n;
      }
    }

    // ---- fused projection: h1_{g-1}, steps 416..511 -> iters 417..512 ----
    if (g >= TSTART + 1) {
      __syncthreads();
      int tp = g - 1 - TSTART;
#pragma unroll
      for (int q = 0; q < 3; ++q) {
        int idx = tid + (q << 8);
        if (idx < 32 * ENCF) {
          int b = idx / ENCF, o = idx - b * ENCF;
          const float* hb = lds + L_HNT + (b << 3);
          const float* wo = lds + L_WP + (o << 3);
          float v = hb[0] * wo[0] + hb[1] * wo[1] + hb[2] * wo[2] + hb[3] * wo[3]
                  + hb[4] * wo[4] + hb[5] * wo[5] + hb[6] * wo[6] + hb[7] * wo[7];
          if (jt == 0) v += bproj[o];
          atomicAdd(outp + ((size_t)(b0 + b) * PREDL + tp) * ENCF + o, v);
        }
      }
    }

    // ---- inter-WG barrier (64 WGs sharing this batch group) ----
    __threadfence();
    __syncthreads();
    if (tid == 0) {
      __hip_atomic_fetch_add(&g_bar[bt], 1u, __ATOMIC_RELEASE, __HIP_MEMORY_SCOPE_AGENT);
      unsigned tgt = 64u * (unsigned)(g + 1);
      while (__hip_atomic_load(&g_bar[bt], __ATOMIC_ACQUIRE, __HIP_MEMORY_SCOPE_AGENT) < tgt)
        __builtin_amdgcn_s_sleep(2);
    }
    __syncthreads();
    __builtin_amdgcn_fence(__ATOMIC_ACQUIRE, "agent");   // make peers' writes visible
  }
}

extern "C" void kernel_launch(void* const* d_in, const int* in_sizes, int n_in,
                              void* d_out, int out_size, void* d_ws, size_t ws_size,
                              hipStream_t stream)
{
  (void)in_sizes; (void)n_in; (void)d_ws; (void)ws_size;
  const float* x_enc  = (const float*)d_in[0];
  const float* W_ih0  = (const float*)d_in[4];
  const float* W_hh0  = (const float*)d_in[5];
  const float* b_ih0  = (const float*)d_in[6];
  const float* b_hh0  = (const float*)d_in[7];
  const float* W_ih1  = (const float*)d_in[8];
  const float* W_hh1  = (const float*)d_in[9];
  const float* b_ih1  = (const float*)d_in[10];
  const float* b_hh1  = (const float*)d_in[11];
  const float* W_proj = (const float*)d_in[12];
  const float* b_proj = (const float*)d_in[13];
  float* outp = (float*)d_out;

  // zero barrier counters (stream-ordered) and output (projection atomics accumulate)
  hipLaunchKernelGGL(zero_bar_kernel, dim3(1), dim3(64), 0, stream);
  hipMemsetAsync(d_out, 0, (size_t)out_size * sizeof(float), stream);

  hipFuncSetAttribute((const void*)gru2_fused,
                      hipFuncAttributeMaxDynamicSharedMemorySize, (int)LDS_BYTES);

  const float* a0 = x_enc;
  const float* a1 = W_ih0;  const float* a2 = W_hh0;
  const float* a3 = b_ih0;  const float* a4 = b_hh0;
  const float* a5 = W_ih1;  const float* a6 = W_hh1;
  const float* a7 = b_ih1;  const float* a8 = b_hh1;
  const float* a9 = W_proj; const float* a10 = b_proj;
  float* a11 = outp;
  void* args[] = { &a0,&a1,&a2,&a3,&a4,&a5,&a6,&a7,&a8,&a9,&a10,&a11 };

  hipError_t e = hipLaunchCooperativeKernel((const void*)gru2_fused,
                                            dim3(NBLK), dim3(NTHR), args,
                                            (unsigned)LDS_BYTES, stream);
  if (e != hipSuccess) {
    // fallback: plain launch (grid == CU count at 1 WG/CU -> co-resident in practice)
    hipLaunchKernelGGL(gru2_fused, dim3(NBLK), dim3(NTHR), LDS_BYTES, stream,
                       x_enc, W_ih0, W_hh0, b_ih0, b_hh0,
                       W_ih1, W_hh1, b_ih1, b_hh1, W_proj, b_proj, outp);
  }
}

// Round 5
// 22134.439 us; speedup vs baseline: 1.6386x; 1.6386x over previous
//
#include <hip/hip_runtime.h>
#include <cmath>

// ============================================================================
// Fused 2-layer GRU (B=128, T=512, d=512) + projection, fp32.
// ONE persistent cooperative kernel, 256 WGs x 256 thr (1 WG/CU).
// Pipeline skew: iter g computes L0 step g AND L1 step g-1.
// r5 changes (driven by r4 counters: FETCH 3.2GB, VALUBusy 11%, conflicts 1.8e9):
//   - h exchange is FENCE-FREE device-coherent: volatile (sc0 sc1) loads/stores
//     go straight to L3; barrier = relaxed atomic add + relaxed spin. No more
//     buffer_wbl2/buffer_inv per iteration -> W_ih1 stream stays L2-resident.
//   - LDS swizzle SWZB spreads b128 reads uniformly over all 8 bank quads.
// ============================================================================

#define TSEQ   512
#define NB     128
#define DM     512
#define ENCF   21
#define PREDL  96
#define TSTART 416
#define NTHR   256
#define NBLK   256

// LDS layout (float indices)
#define L_WHH0 0                    // [24][512] swizzled
#define L_WHH1 (24*DM)              // [24][512] swizzled
#define L_HCH  (2*24*DM)            // [32][128] swizzled h chunk
#define L_SC0  (L_HCH + 32*128)     // [4][32][33] reduce scratch L0
#define L_SC1  (L_SC0 + 4*32*33)    // [4][32][33] reduce scratch L1
#define L_BIA0 (L_SC1 + 4*32*33)    // 48: [0..23]=bhh0 rows, [24..47]=bih0 rows
#define L_BIA1 (L_BIA0 + 48)        // 48
#define L_WIH0 (L_BIA1 + 48)        // [24][24] (K=21 padded)
#define L_XCH  (L_WIH0 + 24*24)     // [32][24] x slice
#define L_WP   (L_XCH + 32*24)      // [21][8] W_proj slice
#define L_HNT  (L_WP + 168)         // [32][8] h1 tile for projection
#define LDS_FLOATS (L_HNT + 256)    // 38,984 floats = 155,936 B  (<160 KiB)
#define LDS_BYTES  (LDS_FLOATS * 4)

// uniform bank-quad swizzle: bits {2,4} from row bits {0,1}
#define SWZB(x) (((((x) & 1) << 2)) | ((((x) & 2)) << 3))

__device__ float g_h0A[NB * DM];
__device__ float g_h0B[NB * DM];
__device__ float g_h1A[NB * DM];
__device__ float g_h1B[NB * DM];
__device__ unsigned g_bar[16];

extern "C" __global__ void zero_bar_kernel() {
  if (threadIdx.x < 16)
    __hip_atomic_store(&g_bar[threadIdx.x], 0u, __ATOMIC_RELAXED, __HIP_MEMORY_SCOPE_AGENT);
}

__device__ __forceinline__ float sigf(float x) { return 1.0f / (1.0f + expf(-x)); }

// device-coherent (sc0 sc1) access helpers: volatile bypasses L1/L2 -> L3.
union DF2 { double d; float2 f; };
__device__ __forceinline__ float2 ld2_dc(const float* p) {
  DF2 u; u.d = *(const volatile double*)p; return u.f;
}
__device__ __forceinline__ float ld_dc(const float* p) { return *(const volatile float*)p; }
__device__ __forceinline__ void st_dc(float* p, float v) { *(volatile float*)p = v; }

extern "C" __global__ __launch_bounds__(NTHR, 1)
void gru2_fused(const float* __restrict__ x_enc,
                const float* __restrict__ Wih0, const float* __restrict__ Whh0,
                const float* __restrict__ bih0, const float* __restrict__ bhh0,
                const float* __restrict__ Wih1, const float* __restrict__ Whh1,
                const float* __restrict__ bih1, const float* __restrict__ bhh1,
                const float* __restrict__ Wproj, const float* __restrict__ bproj,
                float* __restrict__ outp)
{
  extern __shared__ float lds[];

  const int tid = threadIdx.x;
  const int bid = blockIdx.x;
  const int bt  = bid & 3;         // batch group (32 rows), barrier group
  const int jt  = bid >> 2;        // j tile 0..63 (8 hidden units)
  const int b0  = bt << 5;
  const int j0  = jt << 3;
  const int l   = tid & 63;
  const int wv  = tid >> 6;        // wave 0..3
  const int pr  = l & 3;           // row position (bits 0-1)
  const int pb4 = (l >> 2) & 3;    // batch position mod 4 (bits 2-3)
  const int kg  = l >> 4;          // k-group within wave (bits 4-5)

  const float2 z2 = make_float2(0.f, 0.f);

  // ---- one-time staging: W_hh0/W_hh1 (swizzled), W_ih0, biases, W_proj ----
  // tile row r in 0..23 -> global row R = (r>>3)*512 + j0 + (r&7); gates r,z,n
  for (int f = tid; f < 24 * 128; f += NTHR) {
    int r = f >> 7, w4 = f & 127;
    int R = ((r >> 3) << 9) + j0 + (r & 7);
    int dst = r * DM + ((w4 << 2) ^ SWZB(r));          // uniform bank swizzle
    *(float4*)(lds + L_WHH0 + dst) = *(const float4*)(Whh0 + (size_t)R * DM + (w4 << 2));
    *(float4*)(lds + L_WHH1 + dst) = *(const float4*)(Whh1 + (size_t)R * DM + (w4 << 2));
  }
  for (int idx = tid; idx < 24 * ENCF; idx += NTHR) {
    int r = idx / ENCF, kx = idx - r * ENCF;
    int R = ((r >> 3) << 9) + j0 + (r & 7);
    lds[L_WIH0 + r * 24 + kx] = Wih0[R * ENCF + kx];
  }
  if (tid < 24) {
    int R = ((tid >> 3) << 9) + j0 + (tid & 7);
    lds[L_BIA0 + tid]      = bhh0[R];
    lds[L_BIA0 + 24 + tid] = bih0[R];
    lds[L_BIA1 + tid]      = bhh1[R];
    lds[L_BIA1 + 24 + tid] = bih1[R];
  }
  for (int idx = tid; idx < 21 * 8; idx += NTHR) {
    int o = idx >> 3, j = idx & 7;
    lds[L_WP + idx] = Wproj[o * DM + j0 + j];
  }
  // visibility covered by first __syncthreads in the chunk loop

#pragma unroll 1
  for (int g = 0; g <= TSEQ; ++g) {
    // ping-pong: h0_g -> buf0[g&1]; h1_{g-1} -> buf1[(g-1)&1]
    const float* h0r = (g & 1) ? g_h0A : g_h0B;   // h0_{g-1}
    float*       h0w = (g & 1) ? g_h0B : g_h0A;   // h0_g
    const float* h1r = (g & 1) ? g_h1B : g_h1A;   // h1_{g-2}
    float*       h1w = (g & 1) ? g_h1A : g_h1B;   // h1_{g-1}

    // x slice prefetch (regs); clamp at g==TSEQ (L0 result unused there)
    const int gx = (g < TSEQ) ? g : (TSEQ - 1);
    float rx[3];
#pragma unroll
    for (int q = 0; q < 3; ++q) {
      int idx = tid + (q << 8);
      float v = 0.0f;
      if (idx < 32 * ENCF) {
        int row = idx / ENCF, kx = idx - row * ENCF;
        v = x_enc[((size_t)(b0 + row) * TSEQ + gx) * ENCF + kx];
      }
      rx[q] = v;
    }

    float accA[8][6], accX[8][6];
#pragma unroll
    for (int i = 0; i < 8; ++i)
#pragma unroll
      for (int m = 0; m < 6; ++m) { accA[i][m] = 0.0f; accX[i][m] = 0.0f; }

    // h0 chunk-0 prefetch: 8 coherent 8B loads (chunk = 32 rows x 128 floats)
    float2 ph[8];
#pragma unroll
    for (int q = 0; q < 8; ++q) {
      int idx = tid + (q << 8);            // 0..2047 (doubles)
      int row = idx >> 6, c2 = idx & 63;   // 64 doubles per row
      ph[q] = (g == 0) ? z2
            : ld2_dc(h0r + (size_t)(b0 + row) * DM + (c2 << 1));
    }

    // ---- pass A+B: h0_{g-1} x (W_hh0 from LDS, W_ih1 from global) ----
#pragma unroll 1
    for (int c = 0; c < 4; ++c) {
      __syncthreads();                             // prev chunk compute done
#pragma unroll
      for (int q = 0; q < 8; ++q) {
        int idx = tid + (q << 8);
        int row = idx >> 6, cf = (idx & 63) << 1;  // float col (even)
        *(float2*)(lds + L_HCH + row * 128 + (cf ^ SWZB(row))) = ph[q];
      }
      __syncthreads();
      if (c < 3) {
#pragma unroll
        for (int q = 0; q < 8; ++q) {
          int idx = tid + (q << 8);
          int row = idx >> 6, c2 = idx & 63;
          ph[q] = (g == 0) ? z2
                : ld2_dc(h0r + (size_t)(b0 + row) * DM + ((c + 1) << 7) + (c2 << 1));
        }
      }
      // issue global W_ih1 loads (plain cached loads -> stay L2-resident)
      float4 wx[6][2];
#pragma unroll
      for (int m = 0; m < 6; ++m) {
        int r = pr + (m << 2);
        int R = ((r >> 3) << 9) + j0 + (r & 7);
#pragma unroll
        for (int q = 0; q < 2; ++q) {
          int ww = (wv << 3) + (kg << 1) + q;
          wx[m][q] = *(const float4*)(Wih1 + (size_t)R * DM + (((c << 5) + ww) << 2));
        }
      }
#pragma unroll
      for (int q = 0; q < 2; ++q) {
        int ww = (wv << 3) + (kg << 1) + q;
        int colf = ((c << 5) + ww) << 2;
        float4 wh[6];
#pragma unroll
        for (int m = 0; m < 6; ++m) {
          int r = pr + (m << 2);
          wh[m] = *(const float4*)(lds + L_WHH0 + r * DM + (colf ^ SWZB(r)));
        }
#pragma unroll
        for (int i = 0; i < 8; ++i) {
          int b = pb4 + (i << 2);
          float4 hv = *(const float4*)(lds + L_HCH + b * 128 + ((ww << 2) ^ SWZB(b)));
#pragma unroll
          for (int m = 0; m < 6; ++m) {
            accA[i][m] += hv.x * wh[m].x + hv.y * wh[m].y + hv.z * wh[m].z + hv.w * wh[m].w;
            accX[i][m] += hv.x * wx[m][q].x + hv.y * wx[m][q].y + hv.z * wx[m][q].z + hv.w * wx[m][q].w;
          }
        }
      }
    }

    // reduce A -> sc0 (=), X -> sc1 (=)
#pragma unroll
    for (int i = 0; i < 8; ++i)
#pragma unroll
      for (int m = 0; m < 6; ++m) {
        float a = accA[i][m]; a += __shfl_xor(a, 16); a += __shfl_xor(a, 32); accA[i][m] = a;
        float x = accX[i][m]; x += __shfl_xor(x, 16); x += __shfl_xor(x, 32); accX[i][m] = x;
      }
    if (kg == 0) {
#pragma unroll
      for (int i = 0; i < 8; ++i) {
        int b = pb4 + (i << 2);
        float* s0 = lds + L_SC0 + (wv * 32 + b) * 33;
        float* s1 = lds + L_SC1 + (wv * 32 + b) * 33;
#pragma unroll
        for (int m = 0; m < 6; ++m) {
          int r = pr + (m << 2);
          s0[r] = accA[i][m];
          s1[(m < 4) ? r : (r + 8)] = accX[i][m];   // n-gate x-part at 24..31
        }
      }
    }

    // ---- pass C: h1_{g-2} x W_hh1 (LDS) ----
#pragma unroll
    for (int q = 0; q < 8; ++q) {
      int idx = tid + (q << 8);
      int row = idx >> 6, c2 = idx & 63;
      ph[q] = (g <= 1) ? z2
            : ld2_dc(h1r + (size_t)(b0 + row) * DM + (c2 << 1));
    }
#pragma unroll
    for (int i = 0; i < 8; ++i)
#pragma unroll
      for (int m = 0; m < 6; ++m) accA[i][m] = 0.0f;

#pragma unroll 1
    for (int c = 0; c < 4; ++c) {
      __syncthreads();
#pragma unroll
      for (int q = 0; q < 8; ++q) {
        int idx = tid + (q << 8);
        int row = idx >> 6, cf = (idx & 63) << 1;
        *(float2*)(lds + L_HCH + row * 128 + (cf ^ SWZB(row))) = ph[q];
      }
      __syncthreads();
      if (c < 3) {
#pragma unroll
        for (int q = 0; q < 8; ++q) {
          int idx = tid + (q << 8);
          int row = idx >> 6, c2 = idx & 63;
          ph[q] = (g <= 1) ? z2
                : ld2_dc(h1r + (size_t)(b0 + row) * DM + ((c + 1) << 7) + (c2 << 1));
        }
      }
#pragma unroll
      for (int q = 0; q < 2; ++q) {
        int ww = (wv << 3) + (kg << 1) + q;
        int colf = ((c << 5) + ww) << 2;
        float4 wh[6];
#pragma unroll
        for (int m = 0; m < 6; ++m) {
          int r = pr + (m << 2);
          wh[m] = *(const float4*)(lds + L_WHH1 + r * DM + (colf ^ SWZB(r)));
        }
#pragma unroll
        for (int i = 0; i < 8; ++i) {
          int b = pb4 + (i << 2);
          float4 hv = *(const float4*)(lds + L_HCH + b * 128 + ((ww << 2) ^ SWZB(b)));
#pragma unroll
          for (int m = 0; m < 6; ++m)
            accA[i][m] += hv.x * wh[m].x + hv.y * wh[m].y + hv.z * wh[m].z + hv.w * wh[m].w;
        }
      }
    }

    // reduce C -> sc1: rows 0..15 (+=, join x-part), rows 16..23 (=, h-part)
#pragma unroll
    for (int i = 0; i < 8; ++i)
#pragma unroll
      for (int m = 0; m < 6; ++m) {
        float a = accA[i][m]; a += __shfl_xor(a, 16); a += __shfl_xor(a, 32); accA[i][m] = a;
      }
    if (kg == 0) {
#pragma unroll
      for (int i = 0; i < 8; ++i) {
        int b = pb4 + (i << 2);
        float* s1 = lds + L_SC1 + (wv * 32 + b) * 33;
#pragma unroll
        for (int m = 0; m < 6; ++m) {
          int r = pr + (m << 2);
          if (m < 4) s1[r] += accA[i][m];          // same thread wrote '=' above
          else       s1[r]  = accA[i][m];
        }
      }
    }

    // stage x slice for L0 gate threads
#pragma unroll
    for (int q = 0; q < 3; ++q) {
      int idx = tid + (q << 8);
      if (idx < 32 * ENCF) {
        int row = idx / ENCF, kx = idx - row * ENCF;
        lds[L_XCH + row * 24 + kx] = rx[q];
      }
    }
    __syncthreads();

    // ---- gates: thread -> (b = tid>>3, j = tid&7) ----
    {
      int b = tid >> 3, j = tid & 7;
      float sR0 = 0.f, sZ0 = 0.f, sN0 = 0.f;
      float sR1 = 0.f, sZ1 = 0.f, sN1h = 0.f, sN1x = 0.f;
#pragma unroll
      for (int w = 0; w < 4; ++w) {
        const float* s0 = lds + L_SC0 + (w * 32 + b) * 33;
        const float* s1 = lds + L_SC1 + (w * 32 + b) * 33;
        sR0 += s0[j]; sZ0 += s0[8 + j]; sN0 += s0[16 + j];
        sR1 += s1[j]; sZ1 += s1[8 + j]; sN1h += s1[16 + j]; sN1x += s1[24 + j];
      }
      size_t hix = (size_t)(b0 + b) * DM + j0 + j;
      if (g < TSEQ) {
        float xr = 0.f, xz = 0.f, xn = 0.f;
        const float* xrow = lds + L_XCH + b * 24;
#pragma unroll
        for (int k = 0; k < ENCF; ++k) {
          float xv = xrow[k];
          xr += xv * lds[L_WIH0 + j * 24 + k];
          xz += xv * lds[L_WIH0 + (8 + j) * 24 + k];
          xn += xv * lds[L_WIH0 + (16 + j) * 24 + k];
        }
        float h0prev = (g == 0) ? 0.f : ld_dc(h0r + hix);
        float r0 = sigf(xr + lds[L_BIA0 + 24 + j] + sR0 + lds[L_BIA0 + j]);
        float z0 = sigf(xz + lds[L_BIA0 + 32 + j] + sZ0 + lds[L_BIA0 + 8 + j]);
        float n0 = tanhf(xn + lds[L_BIA0 + 40 + j] + r0 * (sN0 + lds[L_BIA0 + 16 + j]));
        st_dc(h0w + hix, (1.0f - z0) * n0 + z0 * h0prev);
      }
      if (g >= 1) {
        float h1prev = (g == 1) ? 0.f : ld_dc(h1r + hix);
        float r1 = sigf(sR1 + lds[L_BIA1 + 24 + j] + lds[L_BIA1 + j]);
        float z1 = sigf(sZ1 + lds[L_BIA1 + 32 + j] + lds[L_BIA1 + 8 + j]);
        float n1 = tanhf(sN1x + lds[L_BIA1 + 40 + j] + r1 * (sN1h + lds[L_BIA1 + 16 + j]));
        float h1n = (1.0f - z1) * n1 + z1 * h1prev;
        st_dc(h1w + hix, h1n);
        lds[L_HNT + (b << 3) + j] = h1n;
      }
    }

    // ---- fused projection: h1_{g-1}, steps 416..511 -> iters 417..512 ----
    if (g >= TSTART + 1) {
      __syncthreads();
      int tp = g - 1 - TSTART;
#pragma unroll
      for (int q = 0; q < 3; ++q) {
        int idx = tid + (q << 8);
        if (idx < 32 * ENCF) {
          int b = idx / ENCF, o = idx - b * ENCF;
          const float* hb = lds + L_HNT + (b << 3);
          const float* wo = lds + L_WP + (o << 3);
          float v = hb[0] * wo[0] + hb[1] * wo[1] + hb[2] * wo[2] + hb[3] * wo[3]
                  + hb[4] * wo[4] + hb[5] * wo[5] + hb[6] * wo[6] + hb[7] * wo[7];
          if (jt == 0) v += bproj[o];
          atomicAdd(outp + ((size_t)(b0 + b) * PREDL + tp) * ENCF + o, v);
        }
      }
    }

    // ---- inter-WG barrier (64 WGs sharing this batch group), fence-free ----
    // __syncthreads drains vmcnt(0) (compiler emits full waitcnt before
    // s_barrier), so all sc0sc1 h-stores are at the coherence point before
    // tid0 publishes. Readers' volatile loads bypass L1/L2 -> no invalidates.
    __syncthreads();
    if (tid == 0) {
      asm volatile("s_waitcnt vmcnt(0) lgkmcnt(0)" ::: "memory");
      __hip_atomic_fetch_add(&g_bar[bt], 1u, __ATOMIC_RELAXED, __HIP_MEMORY_SCOPE_AGENT);
      unsigned tgt = 64u * (unsigned)(g + 1);
      while (__hip_atomic_load(&g_bar[bt], __ATOMIC_RELAXED, __HIP_MEMORY_SCOPE_AGENT) < tgt)
        __builtin_amdgcn_s_sleep(2);
    }
    __syncthreads();
    asm volatile("" ::: "memory");
  }
}

extern "C" void kernel_launch(void* const* d_in, const int* in_sizes, int n_in,
                              void* d_out, int out_size, void* d_ws, size_t ws_size,
                              hipStream_t stream)
{
  (void)in_sizes; (void)n_in; (void)d_ws; (void)ws_size;
  const float* x_enc  = (const float*)d_in[0];
  const float* W_ih0  = (const float*)d_in[4];
  const float* W_hh0  = (const float*)d_in[5];
  const float* b_ih0  = (const float*)d_in[6];
  const float* b_hh0  = (const float*)d_in[7];
  const float* W_ih1  = (const float*)d_in[8];
  const float* W_hh1  = (const float*)d_in[9];
  const float* b_ih1  = (const float*)d_in[10];
  const float* b_hh1  = (const float*)d_in[11];
  const float* W_proj = (const float*)d_in[12];
  const float* b_proj = (const float*)d_in[13];
  float* outp = (float*)d_out;

  // zero barrier counters (stream-ordered) and output (projection atomics accumulate)
  hipLaunchKernelGGL(zero_bar_kernel, dim3(1), dim3(64), 0, stream);
  hipMemsetAsync(d_out, 0, (size_t)out_size * sizeof(float), stream);

  hipFuncSetAttribute((const void*)gru2_fused,
                      hipFuncAttributeMaxDynamicSharedMemorySize, (int)LDS_BYTES);

  const float* a0 = x_enc;
  const float* a1 = W_ih0;  const float* a2 = W_hh0;
  const float* a3 = b_ih0;  const float* a4 = b_hh0;
  const float* a5 = W_ih1;  const float* a6 = W_hh1;
  const float* a7 = b_ih1;  const float* a8 = b_hh1;
  const float* a9 = W_proj; const float* a10 = b_proj;
  float* a11 = outp;
  void* args[] = { &a0,&a1,&a2,&a3,&a4,&a5,&a6,&a7,&a8,&a9,&a10,&a11 };

  hipError_t e = hipLaunchCooperativeKernel((const void*)gru2_fused,
                                            dim3(NBLK), dim3(NTHR), args,
                                            (unsigned)LDS_BYTES, stream);
  if (e != hipSuccess) {
    // fallback: plain launch (grid == CU count at 1 WG/CU -> co-resident in practice)
    hipLaunchKernelGGL(gru2_fused, dim3(NBLK), dim3(NTHR), LDS_BYTES, stream,
                       x_enc, W_ih0, W_hh0, b_ih0, b_hh0,
                       W_ih1, W_hh1, b_ih1, b_hh1, W_proj, b_proj, outp);
  }
}